// Round 9
// baseline (155.444 us; speedup 1.0000x reference)
//
#include <hip/hip_runtime.h>
#include <math.h>

#define NROWS 65536
#define BN_EPS 1e-5f
#define NBLK   1024   // main-kernel grid (64 rows per block)

typedef __attribute__((ext_vector_type(8))) short bf16x8;
typedef __attribute__((ext_vector_type(4))) float f32x4;

// ---- workspace layout (floats) ----
// OFF_PARTIAL : per-row partial                                        [65536]
// OFF_H       : h[row*8+j]                                             [524288]
// OFF_BF      : B-matrix MFMA fragments, bf16 (ushort)                 [8192 fl]
//               frag (gkc,nt): lane l, elem j at
//               Bf[((gkc*2+nt)*64 + l)*8 + j] = B[k=gkc*32+(l>>4)*8+j][n=nt*16+(l&15)]
// OFF_BLKT    : per-block stats transposed blkT[v*1024+blk], v<80      [81920]
// OFF_T       : reduced totals                                         [96]
#define OFF_PARTIAL 0
#define OFF_H       65536
#define OFF_BF      589824
#define OFF_BLKT    598016
#define OFF_T       679936

__device__ inline unsigned short f2bf(float x) {
    union { float f; unsigned u; } v; v.f = x;
    unsigned u = v.u;
    u += 0x7FFFu + ((u >> 16) & 1u);   // RNE
    return (unsigned short)(u >> 16);
}

// K-blocks of L (8 x 64): 0:P(=a*c) 1:C 2:A 3:P^2 | 4:C^2 5:A^2 6:P*C 7:P*A
// Columns of R (27 used, padded to 32):
//  0..15 : s_e   (P->U[f][e], C->B1[f][e], A->B2[f][e])
// 16..23 : h_j   (P->A1[f][j], C->A2[f][j], A->A3[f][j])
//    24  : q     (P->2*QB12, P^2->QU, C^2->QB1, A^2->QB2, PC->2*QUB1, PA->2*QUB2)
//    25  : p1    (P->w1[f], C->b1[f])
//    26  : p2a   (A->b2[f])
__global__ __launch_bounds__(64) void bfrag_kernel(
    const float* __restrict__ W1, const float* __restrict__ B1g,
    const float* __restrict__ W2, const float* __restrict__ B2g,
    const float* __restrict__ lin1_w, const float* __restrict__ w1,
    const float* __restrict__ b1, const float* __restrict__ b2,
    unsigned short* __restrict__ Bf)
{
    int i    = blockIdx.x;        // 0..31
    int gkc  = i >> 1;
    int nt   = i & 1;
    int lane = threadIdx.x;
    int quad = lane >> 4;
    int n    = nt * 16 + (lane & 15);

    unsigned short outv[8];
#pragma unroll
    for (int j = 0; j < 8; j++) {
        int k = gkc * 32 + quad * 8 + j;
        int b = k >> 6, f = k & 63;
        float v = 0.f;
        if (n < 16) {
            if (b == 0)      v = W1[f * 16 + n] + W2[f * 16 + n];
            else if (b == 1) v = B1g[f * 16 + n];
            else if (b == 2) v = B2g[f * 16 + n];
        } else if (n < 24) {
            if (b < 3) {
                const float* lw = lin1_w + (n - 16) * 1024 + f * 16;
                float acc = 0.f;
                for (int e = 0; e < 16; e++) {
                    float src = (b == 0) ? (W1[f * 16 + e] + W2[f * 16 + e])
                              : (b == 1) ? B1g[f * 16 + e] : B2g[f * 16 + e];
                    acc = fmaf(src, lw[e], acc);
                }
                v = acc;
            }
        } else if (n == 24) {
            if (b == 0 || b >= 3) {
                float acc = 0.f;
                for (int e = 0; e < 16; e++) {
                    float U = W1[f * 16 + e] + W2[f * 16 + e];
                    float x = B1g[f * 16 + e], y = B2g[f * 16 + e];
                    float t = (b == 0) ? x * y : (b == 3) ? U * U : (b == 4) ? x * x
                            : (b == 5) ? y * y : (b == 6) ? U * x : U * y;
                    acc += t;
                }
                v = (b == 0 || b == 6 || b == 7) ? 2.f * acc : acc;
            }
        } else if (n == 25) {
            if (b == 0)      v = w1[f];
            else if (b == 1) v = b1[f];
        } else if (n == 26) {
            if (b == 2) v = b2[f];
        }
        outv[j] = f2bf(v);
    }
    unsigned u[4];
#pragma unroll
    for (int p = 0; p < 4; p++)
        u[p] = (unsigned)outv[2 * p] | ((unsigned)outv[2 * p + 1] << 16);
    uint4* dst = (uint4*)(Bf + (size_t)((gkc * 2 + nt) * 64 + lane) * 8);
    *dst = make_uint4(u[0], u[1], u[2], u[3]);
}

// 1024 blocks x 256 threads. Block = 64 rows. L (64 x 256 bf16 half of K=512)
// built in LDS in 2 passes; MFMA 16x16x32 accumulates all 27 outputs.
__global__ __launch_bounds__(256) void main_kernel(
    const float* __restrict__ Xa, const float* __restrict__ Xc,
    const unsigned short* __restrict__ Bf, const float* __restrict__ lin1_b,
    float* __restrict__ ws_partial, float* __restrict__ ws_h,
    float* __restrict__ ws_blkT)
{
    __shared__ unsigned sL[64 * 132];   // 64 rows x 264 bf16 (stride 132 dw = 4 mod 32)
    __shared__ float sD[64][33];        // MFMA output, padded
    __shared__ float scol[256];

    int tid  = threadIdx.x;
    int lane = tid & 63;
    int wv   = tid >> 6;
    int blk  = blockIdx.x;
    int rowbase = blk * 64;

    // ---- phase A: Xc column sums (R6-proven coalesced pattern) ----
    {
        int col = tid & 63, grp = tid >> 6;
        float acc = 0.f;
        for (int r = grp; r < 64; r += 4)
            acc += Xc[(size_t)(rowbase + r) * 64 + col];
        scol[tid] = acc;
    }
    __syncthreads();
    if (tid < 64) {
        float t = scol[tid] + scol[64 + tid] + scol[128 + tid] + scol[192 + tid];
        ws_blkT[(size_t)tid * NBLK + blk] = t;
    }

    // ---- load this thread's a,c (row = tid>>2, f-quarter = tid&3) ----
    int r_local = tid >> 2, qt = tid & 3;
    size_t rbase = ((size_t)rowbase + r_local) * 64 + qt * 16;
    const float4* pa = (const float4*)(Xa + rbase);
    const float4* pc = (const float4*)(Xc + rbase);
    float a_[16], c_[16];
#pragma unroll
    for (int k = 0; k < 4; k++) {
        float4 av = pa[k], cv = pc[k];
        a_[k*4] = av.x; a_[k*4+1] = av.y; a_[k*4+2] = av.z; a_[k*4+3] = av.w;
        c_[k*4] = cv.x; c_[k*4+1] = cv.y; c_[k*4+2] = cv.z; c_[k*4+3] = cv.w;
    }

    int quad = lane >> 4, m = lane & 15;
    const bf16x8* aptr = (const bf16x8*)(sL + (wv * 16 + m) * 132 + quad * 4);
    const bf16x8* bptr = (const bf16x8*)Bf;

    f32x4 acc0 = {0.f, 0.f, 0.f, 0.f};
    f32x4 acc1 = {0.f, 0.f, 0.f, 0.f};

#pragma unroll
    for (int pass = 0; pass < 2; pass++) {
        __syncthreads();   // L region free (prev pass MFMA reads done)
        // build 4 K-blocks of this pass
        unsigned ub[4][8];
#pragma unroll
        for (int e = 0; e < 16; e++) {
            float a = a_[e], c = c_[e], pp = a * c;
            float v4[4];
            if (pass == 0) { v4[0] = pp;    v4[1] = c;     v4[2] = a;      v4[3] = pp * pp; }
            else           { v4[0] = c * c; v4[1] = a * a; v4[2] = pp * c; v4[3] = pp * a; }
#pragma unroll
            for (int bl = 0; bl < 4; bl++) {
                unsigned short h = f2bf(v4[bl]);
                if ((e & 1) == 0) ub[bl][e >> 1] = h;
                else              ub[bl][e >> 1] |= ((unsigned)h << 16);
            }
        }
#pragma unroll
        for (int bl = 0; bl < 4; bl++) {
            unsigned* dst = sL + r_local * 132 + bl * 32 + qt * 8;
            ((uint4*)dst)[0] = make_uint4(ub[bl][0], ub[bl][1], ub[bl][2], ub[bl][3]);
            ((uint4*)dst)[1] = make_uint4(ub[bl][4], ub[bl][5], ub[bl][6], ub[bl][7]);
        }
        __syncthreads();

#pragma unroll 2
        for (int kc = 0; kc < 8; kc++) {
            int gkc = pass * 8 + kc;
            bf16x8 af = aptr[kc * 4];
            bf16x8 b0 = bptr[(size_t)(gkc * 2) * 64 + lane];
            bf16x8 b1 = bptr[(size_t)(gkc * 2 + 1) * 64 + lane];
            acc0 = __builtin_amdgcn_mfma_f32_16x16x32_bf16(af, b0, acc0, 0, 0, 0);
            acc1 = __builtin_amdgcn_mfma_f32_16x16x32_bf16(af, b1, acc1, 0, 0, 0);
        }
    }

    // ---- scatter D to LDS: row=(quad*4+reg), col=lane&15 (verified C/D map) ----
    __syncthreads();
#pragma unroll
    for (int reg = 0; reg < 4; reg++) {
        int rowD = wv * 16 + quad * 4 + reg;
        sD[rowD][m]      = acc0[reg];
        sD[rowD][16 + m] = acc1[reg];
    }
    __syncthreads();

    // ---- per-row epilogue (one thread per row) ----
    if (tid < 64) {
        float S[16], H[8];
#pragma unroll
        for (int e = 0; e < 16; e++) S[e] = sD[tid][e];
#pragma unroll
        for (int j = 0; j < 8; j++) H[j] = sD[tid][16 + j] + lin1_b[j];
        float q   = sD[tid][24];
        float p1  = sD[tid][25];
        float p2a = sD[tid][26];

        float ss = 0.f;
#pragma unroll
        for (int e = 0; e < 16; e++) ss = fmaf(S[e], S[e], ss);
        int rr = rowbase + tid;
        ws_partial[rr] = (p1 + p2a) * (1.f / 64.f) + (ss - q) * (0.5f / 16.f);
        *(float4*)(ws_h + (size_t)rr * 8)     = make_float4(H[0], H[1], H[2], H[3]);
        *(float4*)(ws_h + (size_t)rr * 8 + 4) = make_float4(H[4], H[5], H[6], H[7]);

        float bn[16];
#pragma unroll
        for (int j = 0; j < 8; j++) { bn[j] = H[j]; bn[8 + j] = H[j] * H[j]; }
#pragma unroll
        for (int off = 1; off < 64; off <<= 1) {
#pragma unroll
            for (int i = 0; i < 16; i++) bn[i] += __shfl_xor(bn[i], off);
        }
        if (tid == 0) {
#pragma unroll
            for (int i = 0; i < 16; i++)
                ws_blkT[(size_t)(64 + i) * NBLK + blk] = bn[i];
        }
    }
}

// 80 waves: one per statistic; reduce 1024 block-partials each.
__global__ __launch_bounds__(256) void reduce_kernel(
    const float* __restrict__ ws_blkT, float* __restrict__ T)
{
    int gtid = blockIdx.x * 256 + threadIdx.x;
    int v = gtid >> 6;
    int lane = gtid & 63;
    const float* p = ws_blkT + (size_t)v * NBLK + lane;
    float acc = 0.f;
#pragma unroll
    for (int k = 0; k < 16; k++) acc += p[k * 64];
#pragma unroll
    for (int off = 32; off; off >>= 1) acc += __shfl_xor(acc, off);
    if (lane == 0) T[v] = acc;
}

// 512 blocks x 256 threads: two threads per row. (R8-proven)
__global__ __launch_bounds__(256) void final_kernel(
    const float* __restrict__ Xa, const float* __restrict__ w2,
    const float* __restrict__ gamma, const float* __restrict__ beta,
    const float* __restrict__ lin2_w, const float* __restrict__ lin2_b,
    const float* __restrict__ T, const float* __restrict__ ws_partial,
    const float* __restrict__ ws_h, float* __restrict__ out)
{
    __shared__ float sg[64], sScale[8], sShift[8], sColw[8];
    __shared__ float sBsum;
    int tid = threadIdx.x;
    if (tid < 64) {
        sg[tid] = w2[tid] * (T[tid] * (1.f / 65536.f));
    } else if (tid < 72) {
        int j = tid - 64;
        float mu  = T[64 + j] * (1.f / 65536.f);
        float var = T[72 + j] * (1.f / 65536.f) - mu * mu;
        float sc = gamma[j] / sqrtf(var + BN_EPS);
        sScale[j] = sc;
        sShift[j] = beta[j] - mu * sc;
    } else if (tid < 80) {
        int j = tid - 72;
        sColw[j] = lin2_w[j] + lin2_w[8 + j] + lin2_w[16 + j] + lin2_w[24 + j];
    } else if (tid == 80) {
        sBsum = lin2_b[0] + lin2_b[1] + lin2_b[2] + lin2_b[3];
    }
    __syncthreads();

    int row  = (blockIdx.x * 256 + tid) >> 1;
    int half = tid & 1;
    int fo   = half * 32;

    const float4* xa4 = (const float4*)(Xa + (size_t)row * 64 + fo);
    float p2b = 0.f;
#pragma unroll
    for (int k = 0; k < 8; k++) {
        float4 vv = xa4[k];
        int b = fo + k * 4;
        p2b += vv.x * sg[b] + vv.y * sg[b + 1] + vv.z * sg[b + 2] + vv.w * sg[b + 3];
    }

    float4 hq = *(const float4*)(ws_h + (size_t)row * 8 + half * 4);
    float hv[4] = {hq.x, hq.y, hq.z, hq.w};
    float dmp = 0.f;
#pragma unroll
    for (int jj = 0; jj < 4; jj++) {
        int j = half * 4 + jj;
        float hn = tanhf(hv[jj] * sScale[j] + sShift[j]);
        dmp = fmaf(hn, sColw[j], dmp);
    }

    float val = p2b * (1.f / 64.f) + dmp * 0.25f;
    val += __shfl_xor(val, 1);
    if (!half)
        out[row] = val + ws_partial[row] + sBsum * 0.25f;
}

extern "C" void kernel_launch(void* const* d_in, const int* in_sizes, int n_in,
                              void* d_out, int out_size, void* d_ws, size_t ws_size,
                              hipStream_t stream) {
    const float* Xa        = (const float*)d_in[0];
    const float* Xc        = (const float*)d_in[1];
    const float* w1        = (const float*)d_in[2];
    const float* b1        = (const float*)d_in[3];
    const float* w2        = (const float*)d_in[4];
    const float* b2        = (const float*)d_in[5];
    const float* W1        = (const float*)d_in[6];
    const float* B1        = (const float*)d_in[7];
    const float* W2        = (const float*)d_in[8];
    const float* B2        = (const float*)d_in[9];
    const float* lin1_w    = (const float*)d_in[10];
    const float* lin1_b    = (const float*)d_in[11];
    const float* bn1_gamma = (const float*)d_in[12];
    const float* bn1_beta  = (const float*)d_in[13];
    const float* lin2_w    = (const float*)d_in[14];
    const float* lin2_b    = (const float*)d_in[15];

    float* ws  = (float*)d_ws;
    float* out = (float*)d_out;

    float* ws_partial       = ws + OFF_PARTIAL;
    float* ws_h             = ws + OFF_H;
    unsigned short* ws_bf   = (unsigned short*)(ws + OFF_BF);
    float* ws_blkT          = ws + OFF_BLKT;
    float* ws_T             = ws + OFF_T;

    bfrag_kernel<<<32, 64, 0, stream>>>(W1, B1, W2, B2, lin1_w,
                                        w1, b1, b2, ws_bf);
    main_kernel<<<NBLK, 256, 0, stream>>>(Xa, Xc, ws_bf, lin1_b,
                                          ws_partial, ws_h, ws_blkT);
    reduce_kernel<<<20, 256, 0, stream>>>(ws_blkT, ws_T);
    final_kernel<<<512, 256, 0, stream>>>(Xa, w2, bn1_gamma, bn1_beta,
                                          lin2_w, lin2_b, ws_T,
                                          ws_partial, ws_h, out);
}

// Round 10
// 141.866 us; speedup vs baseline: 1.0957x; 1.0957x over previous
//
#include <hip/hip_runtime.h>
#include <math.h>

#define NROWS 65536
#define BN_EPS 1e-5f
#define NBLK   512   // main-kernel grid (128 rows per block)

// ---- workspace layout (floats) ----
// OFF_PARTIAL : per-row partial                                        [65536]
// OFF_H       : h[row*8+j]                                             [524288]
// OFF_REC     : packed per-feature record rec[f][84]                   [5376]
//               0..15 U=W1+W2 | 16..31 B1 | 32..47 B2 | 48..55 A1
//               56..63 A2 | 64..71 A3 | 72 QU 73 QB1 74 QB2 75 2QUB1
//               76 2QUB2 77 2QB1B2 | 78 w1 79 b1 80 b2 | 81..83 pad
// OFF_BLKT    : per-block stats transposed blkT[v*512+blk], v<80       [40960]
//               v 0..63 Xc colsum, 64..71 sum h_j, 72..79 sum h_j^2
// OFF_T       : reduced totals                                         [96]
#define OFF_PARTIAL 0
#define OFF_H       65536
#define OFF_REC     589824
#define OFF_BLKT    595200
#define OFF_T       636160

// 64 blocks x 64 threads: block f builds rec[f][*].  (proven R4-R8)
__global__ __launch_bounds__(64) void precompute_kernel(
    const float* __restrict__ W1, const float* __restrict__ B1,
    const float* __restrict__ W2, const float* __restrict__ B2,
    const float* __restrict__ lin1_w, const float* __restrict__ w1,
    const float* __restrict__ b1, const float* __restrict__ b2,
    float* __restrict__ rec)
{
    int f = blockIdx.x, t = threadIdx.x;
    __shared__ float u[16], x[16], y[16];
    if (t < 16) {
        float uu = W1[f * 16 + t] + W2[f * 16 + t];
        float xx = B1[f * 16 + t];
        float yy = B2[f * 16 + t];
        u[t] = uu; x[t] = xx; y[t] = yy;
        rec[f * 84 + t]      = uu;
        rec[f * 84 + 16 + t] = xx;
        rec[f * 84 + 32 + t] = yy;
    }
    __syncthreads();
    if (t < 24) {
        int j = t & 7, which = t >> 3;
        const float* src = (which == 0) ? u : (which == 1) ? x : y;
        const float* lw = lin1_w + j * 1024 + f * 16;
        float acc = 0.f;
#pragma unroll
        for (int e = 0; e < 16; e++) acc = fmaf(src[e], lw[e], acc);
        rec[f * 84 + 48 + which * 8 + j] = acc;
    } else if (t < 30) {
        int q = t - 24;
        const float* s1 = (q == 0 || q == 3 || q == 4) ? u : (q == 1 || q == 5) ? x : y;
        const float* s2 = (q == 0) ? u : (q == 1 || q == 3) ? x : y;
        float acc = 0.f;
#pragma unroll
        for (int e = 0; e < 16; e++) acc = fmaf(s1[e], s2[e], acc);
        rec[f * 84 + 72 + q] = (q < 3 ? 1.f : 2.f) * acc;
    } else if (t == 30) {
        rec[f * 84 + 78] = w1[f];
        rec[f * 84 + 79] = b1[f];
        rec[f * 84 + 80] = b2[f];
        rec[f * 84 + 81] = 0.f;
        rec[f * 84 + 82] = 0.f;
        rec[f * 84 + 83] = 0.f;
    }
}

// 512 blocks x 256 threads. Block = 128 rows (2 chunks of 64, lane = row);
// wave w owns f-quarter w. Tables stream via s_load (wave-uniform), each
// record amortized over 128 rows. waves_per_eu max=4 clamps the compiler's
// occupancy target to 4 waves/EU -> 128-VGPR budget -> no scratch spill
// (R7/R8's WRITE_SIZE showed ~13 dw/thread spilled at the default 64-target).
// Residency is grid-limited to 2 blocks/CU (= 2 waves/EU) so no occupancy cost.
__global__ __launch_bounds__(256)
__attribute__((amdgpu_waves_per_eu(2, 4)))
void main_kernel(
    const float* __restrict__ Xa, const float* __restrict__ Xc,
    const float* __restrict__ rec, const float* __restrict__ lin1_b,
    float* __restrict__ ws_partial, float* __restrict__ ws_h,
    float* __restrict__ ws_blkT)
{
    __shared__ float cmb[4][64][29];  // stride 29: conflict-free
    __shared__ float scol[64];        // per-feature block colsum (wave-owned)

    int tid  = threadIdx.x;
    int lane = tid & 63;
    int wv   = tid >> 6;
    int wu   = __builtin_amdgcn_readfirstlane(wv);  // force SGPR path
    int blk  = blockIdx.x;
    int f0   = wu * 16;
    int rowbase = blk * 128;

    // ---- phase B: 2 chunks of 64 rows; table records serve both ----
    size_t rb0 = ((size_t)rowbase + lane) * 64 + f0;
    const float4* pa0 = (const float4*)(Xa + rb0);
    const float4* pc0 = (const float4*)(Xc + rb0);
    const float4* pa1 = (const float4*)(Xa + rb0 + 64 * 64);
    const float4* pc1 = (const float4*)(Xc + rb0 + 64 * 64);

    float s0[16], s1[16], h0[8], h1[8];
#pragma unroll
    for (int e = 0; e < 16; e++) { s0[e] = 0.f; s1[e] = 0.f; }
#pragma unroll
    for (int j = 0; j < 8; j++) { h0[j] = 0.f; h1[j] = 0.f; }
    float p1a = 0.f, p1b = 0.f, p2a0 = 0.f, p2a1 = 0.f, q0 = 0.f, q1 = 0.f;

    const float* recw = rec + (size_t)f0 * 84;
#pragma unroll
    for (int k = 0; k < 4; k++) {
        float4 A0 = pa0[k], C0 = pc0[k];
        float4 A1 = pa1[k], C1 = pc1[k];
        float av0[4] = {A0.x, A0.y, A0.z, A0.w};
        float cv0[4] = {C0.x, C0.y, C0.z, C0.w};
        float av1[4] = {A1.x, A1.y, A1.z, A1.w};
        float cv1[4] = {C1.x, C1.y, C1.z, C1.w};

        // folded Xc colsum: butterfly cv0+cv1 over the 64 lanes (= 128 rows)
#pragma unroll
        for (int uu = 0; uu < 4; uu++) {
            float cs = cv0[uu] + cv1[uu];
#pragma unroll
            for (int off = 1; off < 64; off <<= 1) cs += __shfl_xor(cs, off);
            if (lane == 0) scol[f0 + k * 4 + uu] = cs;
        }

#pragma unroll
        for (int uu = 0; uu < 4; uu++) {
            const float* r = recw + (k * 4 + uu) * 84;  // uniform -> s_load
            {
                float a = av0[uu], c = cv0[uu], pp = a * c;
                p1a  = fmaf(fmaf(r[78], a, r[79]), c, p1a);
                p2a0 = fmaf(a, r[80], p2a0);
                q0 = fmaf(pp * pp, r[72], q0);
                q0 = fmaf(c * c,   r[73], q0);
                q0 = fmaf(a * a,   r[74], q0);
                q0 = fmaf(pp * c,  r[75], q0);
                q0 = fmaf(pp * a,  r[76], q0);
                q0 = fmaf(pp,      r[77], q0);
#pragma unroll
                for (int e = 0; e < 16; e++)
                    s0[e] = fmaf(pp, r[e], fmaf(c, r[16+e], fmaf(a, r[32+e], s0[e])));
#pragma unroll
                for (int j = 0; j < 8; j++)
                    h0[j] = fmaf(pp, r[48+j], fmaf(c, r[56+j], fmaf(a, r[64+j], h0[j])));
            }
            {
                float a = av1[uu], c = cv1[uu], pp = a * c;
                p1b  = fmaf(fmaf(r[78], a, r[79]), c, p1b);
                p2a1 = fmaf(a, r[80], p2a1);
                q1 = fmaf(pp * pp, r[72], q1);
                q1 = fmaf(c * c,   r[73], q1);
                q1 = fmaf(a * a,   r[74], q1);
                q1 = fmaf(pp * c,  r[75], q1);
                q1 = fmaf(pp * a,  r[76], q1);
                q1 = fmaf(pp,      r[77], q1);
#pragma unroll
                for (int e = 0; e < 16; e++)
                    s1[e] = fmaf(pp, r[e], fmaf(c, r[16+e], fmaf(a, r[32+e], s1[e])));
#pragma unroll
                for (int j = 0; j < 8; j++)
                    h1[j] = fmaf(pp, r[48+j], fmaf(c, r[56+j], fmaf(a, r[64+j], h1[j])));
            }
        }
    }

    // ---- cross-wave combine, chunk by chunk (R4/R8-proven logic) ----
    float bn[16];
#pragma unroll
    for (int i = 0; i < 16; i++) bn[i] = 0.f;

#pragma unroll
    for (int g = 0; g < 2; g++) {
        __syncthreads();   // g==0 barrier also publishes scol
#pragma unroll
        for (int e = 0; e < 16; e++) cmb[wv][lane][e] = g ? s1[e] : s0[e];
#pragma unroll
        for (int j = 0; j < 8; j++) cmb[wv][lane][16 + j] = g ? h1[j] : h0[j];
        cmb[wv][lane][24] = g ? p1b : p1a;
        cmb[wv][lane][25] = g ? p2a1 : p2a0;
        cmb[wv][lane][26] = g ? q1 : q0;
        __syncthreads();

        if (tid < 64) {
            float S[16], H[8], P1 = 0.f, P2 = 0.f, Q = 0.f;
#pragma unroll
            for (int e = 0; e < 16; e++) S[e] = 0.f;
#pragma unroll
            for (int j = 0; j < 8; j++) H[j] = 0.f;
#pragma unroll
            for (int w = 0; w < 4; w++) {
#pragma unroll
                for (int e = 0; e < 16; e++) S[e] += cmb[w][tid][e];
#pragma unroll
                for (int j = 0; j < 8; j++) H[j] += cmb[w][tid][16 + j];
                P1 += cmb[w][tid][24];
                P2 += cmb[w][tid][25];
                Q  += cmb[w][tid][26];
            }
#pragma unroll
            for (int j = 0; j < 8; j++) H[j] += lin1_b[j];

            float ss = 0.f;
#pragma unroll
            for (int e = 0; e < 16; e++) ss = fmaf(S[e], S[e], ss);
            int rr = rowbase + g * 64 + tid;
            ws_partial[rr] = (P1 + P2) * (1.f / 64.f) + (ss - Q) * (0.5f / 16.f);
            *(float4*)(ws_h + (size_t)rr * 8)     = make_float4(H[0], H[1], H[2], H[3]);
            *(float4*)(ws_h + (size_t)rr * 8 + 4) = make_float4(H[4], H[5], H[6], H[7]);
#pragma unroll
            for (int j = 0; j < 8; j++) {
                bn[j]     += H[j];
                bn[8 + j] += H[j] * H[j];
            }
        }
    }

    if (tid < 64) {
        // block colsum -> blkT (scol published by the g-loop barriers)
        ws_blkT[(size_t)tid * NBLK + blk] = scol[tid];
#pragma unroll
        for (int off = 1; off < 64; off <<= 1) {
#pragma unroll
            for (int i = 0; i < 16; i++) bn[i] += __shfl_xor(bn[i], off);
        }
        if (tid == 0) {
#pragma unroll
            for (int i = 0; i < 16; i++)
                ws_blkT[(size_t)(64 + i) * NBLK + blk] = bn[i];
        }
    }
}

// 80 waves: one per statistic; reduce 512 block-partials each.
__global__ __launch_bounds__(256) void reduce_kernel(
    const float* __restrict__ ws_blkT, float* __restrict__ T)
{
    int gtid = blockIdx.x * 256 + threadIdx.x;
    int v = gtid >> 6;
    int lane = gtid & 63;
    const float* p = ws_blkT + (size_t)v * NBLK + lane;
    float acc = 0.f;
#pragma unroll
    for (int k = 0; k < 8; k++) acc += p[k * 64];
#pragma unroll
    for (int off = 32; off; off >>= 1) acc += __shfl_xor(acc, off);
    if (lane == 0) T[v] = acc;
}

// 512 blocks x 256 threads: two threads per row. (R8-proven)
__global__ __launch_bounds__(256) void final_kernel(
    const float* __restrict__ Xa, const float* __restrict__ w2,
    const float* __restrict__ gamma, const float* __restrict__ beta,
    const float* __restrict__ lin2_w, const float* __restrict__ lin2_b,
    const float* __restrict__ T, const float* __restrict__ ws_partial,
    const float* __restrict__ ws_h, float* __restrict__ out)
{
    __shared__ float sg[64], sScale[8], sShift[8], sColw[8];
    __shared__ float sBsum;
    int tid = threadIdx.x;
    if (tid < 64) {
        sg[tid] = w2[tid] * (T[tid] * (1.f / 65536.f));
    } else if (tid < 72) {
        int j = tid - 64;
        float mu  = T[64 + j] * (1.f / 65536.f);
        float var = T[72 + j] * (1.f / 65536.f) - mu * mu;
        float sc = gamma[j] / sqrtf(var + BN_EPS);
        sScale[j] = sc;
        sShift[j] = beta[j] - mu * sc;
    } else if (tid < 80) {
        int j = tid - 72;
        sColw[j] = lin2_w[j] + lin2_w[8 + j] + lin2_w[16 + j] + lin2_w[24 + j];
    } else if (tid == 80) {
        sBsum = lin2_b[0] + lin2_b[1] + lin2_b[2] + lin2_b[3];
    }
    __syncthreads();

    int row  = (blockIdx.x * 256 + tid) >> 1;
    int half = tid & 1;
    int fo   = half * 32;

    const float4* xa4 = (const float4*)(Xa + (size_t)row * 64 + fo);
    float p2b = 0.f;
#pragma unroll
    for (int k = 0; k < 8; k++) {
        float4 vv = xa4[k];
        int b = fo + k * 4;
        p2b += vv.x * sg[b] + vv.y * sg[b + 1] + vv.z * sg[b + 2] + vv.w * sg[b + 3];
    }

    float4 hq = *(const float4*)(ws_h + (size_t)row * 8 + half * 4);
    float hv[4] = {hq.x, hq.y, hq.z, hq.w};
    float dmp = 0.f;
#pragma unroll
    for (int jj = 0; jj < 4; jj++) {
        int j = half * 4 + jj;
        float hn = tanhf(hv[jj] * sScale[j] + sShift[j]);
        dmp = fmaf(hn, sColw[j], dmp);
    }

    float val = p2b * (1.f / 64.f) + dmp * 0.25f;
    val += __shfl_xor(val, 1);
    if (!half)
        out[row] = val + ws_partial[row] + sBsum * 0.25f;
}

extern "C" void kernel_launch(void* const* d_in, const int* in_sizes, int n_in,
                              void* d_out, int out_size, void* d_ws, size_t ws_size,
                              hipStream_t stream) {
    const float* Xa        = (const float*)d_in[0];
    const float* Xc        = (const float*)d_in[1];
    const float* w1        = (const float*)d_in[2];
    const float* b1        = (const float*)d_in[3];
    const float* w2        = (const float*)d_in[4];
    const float* b2        = (const float*)d_in[5];
    const float* W1        = (const float*)d_in[6];
    const float* B1        = (const float*)d_in[7];
    const float* W2        = (const float*)d_in[8];
    const float* B2        = (const float*)d_in[9];
    const float* lin1_w    = (const float*)d_in[10];
    const float* lin1_b    = (const float*)d_in[11];
    const float* bn1_gamma = (const float*)d_in[12];
    const float* bn1_beta  = (const float*)d_in[13];
    const float* lin2_w    = (const float*)d_in[14];
    const float* lin2_b    = (const float*)d_in[15];

    float* ws  = (float*)d_ws;
    float* out = (float*)d_out;

    float* ws_partial = ws + OFF_PARTIAL;
    float* ws_h       = ws + OFF_H;
    float* ws_rec     = ws + OFF_REC;
    float* ws_blkT    = ws + OFF_BLKT;
    float* ws_T       = ws + OFF_T;

    precompute_kernel<<<64, 64, 0, stream>>>(W1, B1, W2, B2, lin1_w,
                                             w1, b1, b2, ws_rec);
    main_kernel<<<NBLK, 256, 0, stream>>>(Xa, Xc, ws_rec, lin1_b,
                                          ws_partial, ws_h, ws_blkT);
    reduce_kernel<<<20, 256, 0, stream>>>(ws_blkT, ws_T);
    final_kernel<<<512, 256, 0, stream>>>(Xa, w2, bn1_gamma, bn1_beta,
                                          lin2_w, lin2_b, ws_T,
                                          ws_partial, ws_h, out);
}

// Round 11
// 130.606 us; speedup vs baseline: 1.1902x; 1.0862x over previous
//
#include <hip/hip_runtime.h>
#include <math.h>

#define NROWS 65536
#define BN_EPS 1e-5f
#define NBLK   512   // main-kernel grid (128 rows per block)

// ---- workspace layout (floats) ----
// OFF_PARTIAL : per-row partial                                        [65536]
// OFF_H       : h[row*8+j]                                             [524288]
// OFF_REC     : packed per-feature record rec[f][84]                   [5376]
//               0..15 U=W1+W2 | 16..31 B1 | 32..47 B2 | 48..55 A1
//               56..63 A2 | 64..71 A3 | 72 QU 73 QB1 74 QB2 75 2QUB1
//               76 2QUB2 77 2QB1B2 | 78 w1 79 b1 80 b2 | 81..83 pad
// OFF_BLKT    : per-block stats transposed blkT[v*512+blk], v<80       [40960]
//               v 0..63 Xc colsum, 64..71 sum h_j, 72..79 sum h_j^2
// OFF_T       : reduced totals                                         [96]
#define OFF_PARTIAL 0
#define OFF_H       65536
#define OFF_REC     589824
#define OFF_BLKT    595200
#define OFF_T       636160

// 64 blocks x 64 threads: block f builds rec[f][*].  (proven R4-R8)
__global__ __launch_bounds__(64) void precompute_kernel(
    const float* __restrict__ W1, const float* __restrict__ B1,
    const float* __restrict__ W2, const float* __restrict__ B2,
    const float* __restrict__ lin1_w, const float* __restrict__ w1,
    const float* __restrict__ b1, const float* __restrict__ b2,
    float* __restrict__ rec)
{
    int f = blockIdx.x, t = threadIdx.x;
    __shared__ float u[16], x[16], y[16];
    if (t < 16) {
        float uu = W1[f * 16 + t] + W2[f * 16 + t];
        float xx = B1[f * 16 + t];
        float yy = B2[f * 16 + t];
        u[t] = uu; x[t] = xx; y[t] = yy;
        rec[f * 84 + t]      = uu;
        rec[f * 84 + 16 + t] = xx;
        rec[f * 84 + 32 + t] = yy;
    }
    __syncthreads();
    if (t < 24) {
        int j = t & 7, which = t >> 3;
        const float* src = (which == 0) ? u : (which == 1) ? x : y;
        const float* lw = lin1_w + j * 1024 + f * 16;
        float acc = 0.f;
#pragma unroll
        for (int e = 0; e < 16; e++) acc = fmaf(src[e], lw[e], acc);
        rec[f * 84 + 48 + which * 8 + j] = acc;
    } else if (t < 30) {
        int q = t - 24;
        const float* s1 = (q == 0 || q == 3 || q == 4) ? u : (q == 1 || q == 5) ? x : y;
        const float* s2 = (q == 0) ? u : (q == 1 || q == 3) ? x : y;
        float acc = 0.f;
#pragma unroll
        for (int e = 0; e < 16; e++) acc = fmaf(s1[e], s2[e], acc);
        rec[f * 84 + 72 + q] = (q < 3 ? 1.f : 2.f) * acc;
    } else if (t == 30) {
        rec[f * 84 + 78] = w1[f];
        rec[f * 84 + 79] = b1[f];
        rec[f * 84 + 80] = b2[f];
        rec[f * 84 + 81] = 0.f;
        rec[f * 84 + 82] = 0.f;
        rec[f * 84 + 83] = 0.f;
    }
}

// 512 blocks x 256 threads. Block = 128 rows (2 chunks of 64, lane = row);
// wave w owns f-quarter w. Tables stream via s_load (wave-uniform), each
// record amortized over 128 rows (R8-proven structure, 129 us total).
// ONE change vs R8: waves_per_eu(2,4) lifts the compiler's 64-VGPR
// occupancy target to a 128 budget -> removes the ~13 dw/thread spill
// (R10 evidence: VGPR 64->100, WRITE 16->6.6 MB). Colsum butterflies stay
// OUT of the hot loop: shfl = DS ops share lgkmcnt with s_load (R10 lesson).
__global__ __launch_bounds__(256)
__attribute__((amdgpu_waves_per_eu(2, 4)))
void main_kernel(
    const float* __restrict__ Xa, const float* __restrict__ Xc,
    const float* __restrict__ rec, const float* __restrict__ lin1_b,
    float* __restrict__ ws_partial, float* __restrict__ ws_h,
    float* __restrict__ ws_blkT)
{
    __shared__ float cmb[4][64][29];  // stride 29: conflict-free
    __shared__ float scol[256];

    int tid  = threadIdx.x;
    int lane = tid & 63;
    int wv   = tid >> 6;
    int wu   = __builtin_amdgcn_readfirstlane(wv);  // force SGPR path
    int blk  = blockIdx.x;
    int f0   = wu * 16;
    int rowbase = blk * 128;

    // ---- phase A: Xc column sums over 128 rows, coalesced (R6-proven) ----
    {
        int col = tid & 63, grp = tid >> 6;
        float acc = 0.f;
        for (int r = grp; r < 128; r += 4)
            acc += Xc[(size_t)(rowbase + r) * 64 + col];
        scol[tid] = acc;
    }
    __syncthreads();
    if (tid < 64) {
        float t = scol[tid] + scol[64 + tid] + scol[128 + tid] + scol[192 + tid];
        ws_blkT[(size_t)tid * NBLK + blk] = t;
    }

    // ---- phase B: 2 chunks of 64 rows; table records serve both ----
    size_t rb0 = ((size_t)rowbase + lane) * 64 + f0;
    const float4* pa0 = (const float4*)(Xa + rb0);
    const float4* pc0 = (const float4*)(Xc + rb0);
    const float4* pa1 = (const float4*)(Xa + rb0 + 64 * 64);
    const float4* pc1 = (const float4*)(Xc + rb0 + 64 * 64);

    float s0[16], s1[16], h0[8], h1[8];
#pragma unroll
    for (int e = 0; e < 16; e++) { s0[e] = 0.f; s1[e] = 0.f; }
#pragma unroll
    for (int j = 0; j < 8; j++) { h0[j] = 0.f; h1[j] = 0.f; }
    float p1a = 0.f, p1b = 0.f, p2a0 = 0.f, p2a1 = 0.f, q0 = 0.f, q1 = 0.f;

    const float* recw = rec + (size_t)f0 * 84;
#pragma unroll
    for (int k = 0; k < 4; k++) {
        float4 A0 = pa0[k], C0 = pc0[k];
        float4 A1 = pa1[k], C1 = pc1[k];
        float av0[4] = {A0.x, A0.y, A0.z, A0.w};
        float cv0[4] = {C0.x, C0.y, C0.z, C0.w};
        float av1[4] = {A1.x, A1.y, A1.z, A1.w};
        float cv1[4] = {C1.x, C1.y, C1.z, C1.w};
#pragma unroll
        for (int uu = 0; uu < 4; uu++) {
            const float* r = recw + (k * 4 + uu) * 84;  // uniform -> s_load
            {
                float a = av0[uu], c = cv0[uu], pp = a * c;
                p1a  = fmaf(fmaf(r[78], a, r[79]), c, p1a);
                p2a0 = fmaf(a, r[80], p2a0);
                q0 = fmaf(pp * pp, r[72], q0);
                q0 = fmaf(c * c,   r[73], q0);
                q0 = fmaf(a * a,   r[74], q0);
                q0 = fmaf(pp * c,  r[75], q0);
                q0 = fmaf(pp * a,  r[76], q0);
                q0 = fmaf(pp,      r[77], q0);
#pragma unroll
                for (int e = 0; e < 16; e++)
                    s0[e] = fmaf(pp, r[e], fmaf(c, r[16+e], fmaf(a, r[32+e], s0[e])));
#pragma unroll
                for (int j = 0; j < 8; j++)
                    h0[j] = fmaf(pp, r[48+j], fmaf(c, r[56+j], fmaf(a, r[64+j], h0[j])));
            }
            {
                float a = av1[uu], c = cv1[uu], pp = a * c;
                p1b  = fmaf(fmaf(r[78], a, r[79]), c, p1b);
                p2a1 = fmaf(a, r[80], p2a1);
                q1 = fmaf(pp * pp, r[72], q1);
                q1 = fmaf(c * c,   r[73], q1);
                q1 = fmaf(a * a,   r[74], q1);
                q1 = fmaf(pp * c,  r[75], q1);
                q1 = fmaf(pp * a,  r[76], q1);
                q1 = fmaf(pp,      r[77], q1);
#pragma unroll
                for (int e = 0; e < 16; e++)
                    s1[e] = fmaf(pp, r[e], fmaf(c, r[16+e], fmaf(a, r[32+e], s1[e])));
#pragma unroll
                for (int j = 0; j < 8; j++)
                    h1[j] = fmaf(pp, r[48+j], fmaf(c, r[56+j], fmaf(a, r[64+j], h1[j])));
            }
        }
    }

    // ---- cross-wave combine, chunk by chunk (R4/R8-proven logic) ----
    float bn[16];
#pragma unroll
    for (int i = 0; i < 16; i++) bn[i] = 0.f;

#pragma unroll
    for (int g = 0; g < 2; g++) {
        __syncthreads();
#pragma unroll
        for (int e = 0; e < 16; e++) cmb[wv][lane][e] = g ? s1[e] : s0[e];
#pragma unroll
        for (int j = 0; j < 8; j++) cmb[wv][lane][16 + j] = g ? h1[j] : h0[j];
        cmb[wv][lane][24] = g ? p1b : p1a;
        cmb[wv][lane][25] = g ? p2a1 : p2a0;
        cmb[wv][lane][26] = g ? q1 : q0;
        __syncthreads();

        if (tid < 64) {
            float S[16], H[8], P1 = 0.f, P2 = 0.f, Q = 0.f;
#pragma unroll
            for (int e = 0; e < 16; e++) S[e] = 0.f;
#pragma unroll
            for (int j = 0; j < 8; j++) H[j] = 0.f;
#pragma unroll
            for (int w = 0; w < 4; w++) {
#pragma unroll
                for (int e = 0; e < 16; e++) S[e] += cmb[w][tid][e];
#pragma unroll
                for (int j = 0; j < 8; j++) H[j] += cmb[w][tid][16 + j];
                P1 += cmb[w][tid][24];
                P2 += cmb[w][tid][25];
                Q  += cmb[w][tid][26];
            }
#pragma unroll
            for (int j = 0; j < 8; j++) H[j] += lin1_b[j];

            float ss = 0.f;
#pragma unroll
            for (int e = 0; e < 16; e++) ss = fmaf(S[e], S[e], ss);
            int rr = rowbase + g * 64 + tid;
            ws_partial[rr] = (P1 + P2) * (1.f / 64.f) + (ss - Q) * (0.5f / 16.f);
            *(float4*)(ws_h + (size_t)rr * 8)     = make_float4(H[0], H[1], H[2], H[3]);
            *(float4*)(ws_h + (size_t)rr * 8 + 4) = make_float4(H[4], H[5], H[6], H[7]);
#pragma unroll
            for (int j = 0; j < 8; j++) {
                bn[j]     += H[j];
                bn[8 + j] += H[j] * H[j];
            }
        }
    }

    if (tid < 64) {
#pragma unroll
        for (int off = 1; off < 64; off <<= 1) {
#pragma unroll
            for (int i = 0; i < 16; i++) bn[i] += __shfl_xor(bn[i], off);
        }
        if (tid == 0) {
#pragma unroll
            for (int i = 0; i < 16; i++)
                ws_blkT[(size_t)(64 + i) * NBLK + blk] = bn[i];
        }
    }
}

// 80 waves: one per statistic; reduce 512 block-partials each.
__global__ __launch_bounds__(256) void reduce_kernel(
    const float* __restrict__ ws_blkT, float* __restrict__ T)
{
    int gtid = blockIdx.x * 256 + threadIdx.x;
    int v = gtid >> 6;
    int lane = gtid & 63;
    const float* p = ws_blkT + (size_t)v * NBLK + lane;
    float acc = 0.f;
#pragma unroll
    for (int k = 0; k < 8; k++) acc += p[k * 64];
#pragma unroll
    for (int off = 32; off; off >>= 1) acc += __shfl_xor(acc, off);
    if (lane == 0) T[v] = acc;
}

// 512 blocks x 256 threads: two threads per row. (R8-proven)
__global__ __launch_bounds__(256) void final_kernel(
    const float* __restrict__ Xa, const float* __restrict__ w2,
    const float* __restrict__ gamma, const float* __restrict__ beta,
    const float* __restrict__ lin2_w, const float* __restrict__ lin2_b,
    const float* __restrict__ T, const float* __restrict__ ws_partial,
    const float* __restrict__ ws_h, float* __restrict__ out)
{
    __shared__ float sg[64], sScale[8], sShift[8], sColw[8];
    __shared__ float sBsum;
    int tid = threadIdx.x;
    if (tid < 64) {
        sg[tid] = w2[tid] * (T[tid] * (1.f / 65536.f));
    } else if (tid < 72) {
        int j = tid - 64;
        float mu  = T[64 + j] * (1.f / 65536.f);
        float var = T[72 + j] * (1.f / 65536.f) - mu * mu;
        float sc = gamma[j] / sqrtf(var + BN_EPS);
        sScale[j] = sc;
        sShift[j] = beta[j] - mu * sc;
    } else if (tid < 80) {
        int j = tid - 72;
        sColw[j] = lin2_w[j] + lin2_w[8 + j] + lin2_w[16 + j] + lin2_w[24 + j];
    } else if (tid == 80) {
        sBsum = lin2_b[0] + lin2_b[1] + lin2_b[2] + lin2_b[3];
    }
    __syncthreads();

    int row  = (blockIdx.x * 256 + tid) >> 1;
    int half = tid & 1;
    int fo   = half * 32;

    const float4* xa4 = (const float4*)(Xa + (size_t)row * 64 + fo);
    float p2b = 0.f;
#pragma unroll
    for (int k = 0; k < 8; k++) {
        float4 vv = xa4[k];
        int b = fo + k * 4;
        p2b += vv.x * sg[b] + vv.y * sg[b + 1] + vv.z * sg[b + 2] + vv.w * sg[b + 3];
    }

    float4 hq = *(const float4*)(ws_h + (size_t)row * 8 + half * 4);
    float hv[4] = {hq.x, hq.y, hq.z, hq.w};
    float dmp = 0.f;
#pragma unroll
    for (int jj = 0; jj < 4; jj++) {
        int j = half * 4 + jj;
        float hn = tanhf(hv[jj] * sScale[j] + sShift[j]);
        dmp = fmaf(hn, sColw[j], dmp);
    }

    float val = p2b * (1.f / 64.f) + dmp * 0.25f;
    val += __shfl_xor(val, 1);
    if (!half)
        out[row] = val + ws_partial[row] + sBsum * 0.25f;
}

extern "C" void kernel_launch(void* const* d_in, const int* in_sizes, int n_in,
                              void* d_out, int out_size, void* d_ws, size_t ws_size,
                              hipStream_t stream) {
    const float* Xa        = (const float*)d_in[0];
    const float* Xc        = (const float*)d_in[1];
    const float* w1        = (const float*)d_in[2];
    const float* b1        = (const float*)d_in[3];
    const float* w2        = (const float*)d_in[4];
    const float* b2        = (const float*)d_in[5];
    const float* W1        = (const float*)d_in[6];
    const float* B1        = (const float*)d_in[7];
    const float* W2        = (const float*)d_in[8];
    const float* B2        = (const float*)d_in[9];
    const float* lin1_w    = (const float*)d_in[10];
    const float* lin1_b    = (const float*)d_in[11];
    const float* bn1_gamma = (const float*)d_in[12];
    const float* bn1_beta  = (const float*)d_in[13];
    const float* lin2_w    = (const float*)d_in[14];
    const float* lin2_b    = (const float*)d_in[15];

    float* ws  = (float*)d_ws;
    float* out = (float*)d_out;

    float* ws_partial = ws + OFF_PARTIAL;
    float* ws_h       = ws + OFF_H;
    float* ws_rec     = ws + OFF_REC;
    float* ws_blkT    = ws + OFF_BLKT;
    float* ws_T       = ws + OFF_T;

    precompute_kernel<<<64, 64, 0, stream>>>(W1, B1, W2, B2, lin1_w,
                                             w1, b1, b2, ws_rec);
    main_kernel<<<NBLK, 256, 0, stream>>>(Xa, Xc, ws_rec, lin1_b,
                                          ws_partial, ws_h, ws_blkT);
    reduce_kernel<<<20, 256, 0, stream>>>(ws_blkT, ws_T);
    final_kernel<<<512, 256, 0, stream>>>(Xa, w2, bn1_gamma, bn1_beta,
                                          lin2_w, lin2_b, ws_T,
                                          ws_partial, ws_h, out);
}

// Round 12
// 128.539 us; speedup vs baseline: 1.2093x; 1.0161x over previous
//
#include <hip/hip_runtime.h>
#include <math.h>

#define NROWS 65536
#define BN_EPS 1e-5f
#define NBLK   1024   // main-kernel grid (64 rows per block)

// ---- workspace layout (floats) ----
// OFF_PARTIAL : per-row partial                                        [65536]
// OFF_H       : h[row*8+j]                                             [524288]
// OFF_REC     : packed per-feature record rec[f][84]                   [5376]
//               0..15 U=W1+W2 | 16..31 B1 | 32..47 B2 | 48..55 A1
//               56..63 A2 | 64..71 A3 | 72 QU 73 QB1 74 QB2 75 2QUB1
//               76 2QUB2 77 2QB1B2 | 78 w1 79 b1 80 b2 | 81..83 pad
// OFF_BLKT    : per-block stats transposed blkT[v*1024+blk], v<80      [81920]
//               v 0..63 Xc colsum, 64..71 sum h_j, 72..79 sum h_j^2
// OFF_T       : reduced totals                                         [96]
#define OFF_PARTIAL 0
#define OFF_H       65536
#define OFF_REC     589824
#define OFF_BLKT    595200
#define OFF_T       677120

// 64 blocks x 64 threads: block f builds rec[f][*].  (proven R4-R11)
__global__ __launch_bounds__(64) void precompute_kernel(
    const float* __restrict__ W1, const float* __restrict__ B1,
    const float* __restrict__ W2, const float* __restrict__ B2,
    const float* __restrict__ lin1_w, const float* __restrict__ w1,
    const float* __restrict__ b1, const float* __restrict__ b2,
    float* __restrict__ rec)
{
    int f = blockIdx.x, t = threadIdx.x;
    __shared__ float u[16], x[16], y[16];
    if (t < 16) {
        float uu = W1[f * 16 + t] + W2[f * 16 + t];
        float xx = B1[f * 16 + t];
        float yy = B2[f * 16 + t];
        u[t] = uu; x[t] = xx; y[t] = yy;
        rec[f * 84 + t]      = uu;
        rec[f * 84 + 16 + t] = xx;
        rec[f * 84 + 32 + t] = yy;
    }
    __syncthreads();
    if (t < 24) {
        int j = t & 7, which = t >> 3;
        const float* src = (which == 0) ? u : (which == 1) ? x : y;
        const float* lw = lin1_w + j * 1024 + f * 16;
        float acc = 0.f;
#pragma unroll
        for (int e = 0; e < 16; e++) acc = fmaf(src[e], lw[e], acc);
        rec[f * 84 + 48 + which * 8 + j] = acc;
    } else if (t < 30) {
        int q = t - 24;
        const float* s1 = (q == 0 || q == 3 || q == 4) ? u : (q == 1 || q == 5) ? x : y;
        const float* s2 = (q == 0) ? u : (q == 1 || q == 3) ? x : y;
        float acc = 0.f;
#pragma unroll
        for (int e = 0; e < 16; e++) acc = fmaf(s1[e], s2[e], acc);
        rec[f * 84 + 72 + q] = (q < 3 ? 1.f : 2.f) * acc;
    } else if (t == 30) {
        rec[f * 84 + 78] = w1[f];
        rec[f * 84 + 79] = b1[f];
        rec[f * 84 + 80] = b2[f];
        rec[f * 84 + 81] = 0.f;
        rec[f * 84 + 82] = 0.f;
        rec[f * 84 + 83] = 0.f;
    }
}

// 1024 blocks x 256 threads. Block = 64 rows (lane = row); wave w owns
// f-quarter w. Table streams via LDS wave-uniform broadcasts (conflict-free,
// lgkmcnt-pipelined) instead of the SGPR-starved s_load path (R11 evidence:
// 84-dword records can't prefetch in ~112 SGPRs -> 88% stall).
// waves_per_eu(2,4) = 128-VGPR budget, no spill (R11-proven).
// unroll 1 prevents R5's full-unroll ds_read hoisting -> VGPR explosion.
// Colsum butterfly AFTER the hot loop (R10 lesson: shfl shares lgkmcnt).
__global__ __launch_bounds__(256)
__attribute__((amdgpu_waves_per_eu(2, 4)))
void main_kernel(
    const float* __restrict__ Xa, const float* __restrict__ Xc,
    const float* __restrict__ rec, const float* __restrict__ lin1_b,
    float* __restrict__ ws_partial, float* __restrict__ ws_h,
    float* __restrict__ ws_blkT)
{
    // [0,5376) = rec staging during phase B; then cmb[4][64][29] (aliased,
    // barrier-separated -- R4-proven)
    __shared__ __align__(16) float smem[7424];

    int tid  = threadIdx.x;
    int lane = tid & 63;
    int wv   = tid >> 6;
    int wu   = __builtin_amdgcn_readfirstlane(wv);
    int blk  = blockIdx.x;
    int f0   = wu * 16;
    int row  = blk * 64 + lane;

    // stage rec -> LDS (coalesced float4, ~21.5 KB)
    {
        const float4* src = (const float4*)rec;
        float4* dst = (float4*)smem;
        for (int i = tid; i < 1344; i += 256) dst[i] = src[i];
    }

    // per-lane a/c (R7-proven register layout)
    const float4* pa = (const float4*)(Xa + (size_t)row * 64 + f0);
    const float4* pc = (const float4*)(Xc + (size_t)row * 64 + f0);
    float a_[16], c_[16];
#pragma unroll
    for (int k = 0; k < 4; k++) {
        float4 av = pa[k], cv = pc[k];
        a_[k * 4] = av.x; a_[k * 4 + 1] = av.y; a_[k * 4 + 2] = av.z; a_[k * 4 + 3] = av.w;
        c_[k * 4] = cv.x; c_[k * 4 + 1] = cv.y; c_[k * 4 + 2] = cv.z; c_[k * 4 + 3] = cv.w;
    }
    __syncthreads();   // rec staged

    float s[16], hh[8];
#pragma unroll
    for (int e = 0; e < 16; e++) s[e] = 0.f;
#pragma unroll
    for (int j = 0; j < 8; j++) hh[j] = 0.f;
    float p1 = 0.f, p2a = 0.f, qsum = 0.f;

    const float* recw = smem + f0 * 84;
#pragma unroll 1
    for (int i = 0; i < 16; i++) {
        const float* r = recw + i * 84;   // wave-uniform -> LDS broadcast
        float a = a_[i], c = c_[i];
        float pp = a * c;
        p1  = fmaf(fmaf(r[78], a, r[79]), c, p1);
        p2a = fmaf(a, r[80], p2a);
        qsum = fmaf(pp * pp, r[72], qsum);
        qsum = fmaf(c * c,   r[73], qsum);
        qsum = fmaf(a * a,   r[74], qsum);
        qsum = fmaf(pp * c,  r[75], qsum);
        qsum = fmaf(pp * a,  r[76], qsum);
        qsum = fmaf(pp,      r[77], qsum);
#pragma unroll
        for (int e = 0; e < 16; e++)
            s[e] = fmaf(pp, r[e], fmaf(c, r[16 + e], fmaf(a, r[32 + e], s[e])));
#pragma unroll
        for (int j = 0; j < 8; j++)
            hh[j] = fmaf(pp, r[48 + j], fmaf(c, r[56 + j], fmaf(a, r[64 + j], hh[j])));
    }

    // Xc column sums (butterfly on retained c_, outside the hot loop)
    {
        float cs[16];
#pragma unroll
        for (int i = 0; i < 16; i++) cs[i] = c_[i];
#pragma unroll
        for (int off = 1; off < 64; off <<= 1) {
#pragma unroll
            for (int i = 0; i < 16; i++) cs[i] += __shfl_xor(cs[i], off);
        }
        if (lane == 0) {
#pragma unroll
            for (int i = 0; i < 16; i++)
                ws_blkT[(size_t)(f0 + i) * NBLK + blk] = cs[i];
        }
    }

    // cross-wave combine (aliases rec region; barrier retires table reads)
    __syncthreads();
    {
        float* cmb = smem + (wv * 64 + lane) * 29;
#pragma unroll
        for (int e = 0; e < 16; e++) cmb[e] = s[e];
#pragma unroll
        for (int j = 0; j < 8; j++) cmb[16 + j] = hh[j];
        cmb[24] = p1;
        cmb[25] = p2a;
        cmb[26] = qsum;
    }
    __syncthreads();

    if (tid < 64) {
        float S[16], H[8], P1 = 0.f, P2 = 0.f, Q = 0.f;
#pragma unroll
        for (int e = 0; e < 16; e++) S[e] = 0.f;
#pragma unroll
        for (int j = 0; j < 8; j++) H[j] = 0.f;
#pragma unroll
        for (int w = 0; w < 4; w++) {
            const float* c2 = smem + (w * 64 + tid) * 29;
#pragma unroll
            for (int e = 0; e < 16; e++) S[e] += c2[e];
#pragma unroll
            for (int j = 0; j < 8; j++) H[j] += c2[16 + j];
            P1 += c2[24];
            P2 += c2[25];
            Q  += c2[26];
        }
#pragma unroll
        for (int j = 0; j < 8; j++) H[j] += lin1_b[j];

        float ss = 0.f;
#pragma unroll
        for (int e = 0; e < 16; e++) ss = fmaf(S[e], S[e], ss);
        int rr = blk * 64 + tid;
        ws_partial[rr] = (P1 + P2) * (1.f / 64.f) + (ss - Q) * (0.5f / 16.f);
        *(float4*)(ws_h + (size_t)rr * 8)     = make_float4(H[0], H[1], H[2], H[3]);
        *(float4*)(ws_h + (size_t)rr * 8 + 4) = make_float4(H[4], H[5], H[6], H[7]);

        // BN partials over this block's 64 rows
        float bn[16];
#pragma unroll
        for (int j = 0; j < 8; j++) { bn[j] = H[j]; bn[8 + j] = H[j] * H[j]; }
#pragma unroll
        for (int off = 1; off < 64; off <<= 1) {
#pragma unroll
            for (int i = 0; i < 16; i++) bn[i] += __shfl_xor(bn[i], off);
        }
        if (tid == 0) {
#pragma unroll
            for (int i = 0; i < 16; i++)
                ws_blkT[(size_t)(64 + i) * NBLK + blk] = bn[i];
        }
    }
}

// 80 waves: one per statistic; reduce 1024 block-partials each.
__global__ __launch_bounds__(256) void reduce_kernel(
    const float* __restrict__ ws_blkT, float* __restrict__ T)
{
    int gtid = blockIdx.x * 256 + threadIdx.x;
    int v = gtid >> 6;
    int lane = gtid & 63;
    const float* p = ws_blkT + (size_t)v * NBLK + lane;
    float acc = 0.f;
#pragma unroll
    for (int k = 0; k < 16; k++) acc += p[k * 64];
#pragma unroll
    for (int off = 32; off; off >>= 1) acc += __shfl_xor(acc, off);
    if (lane == 0) T[v] = acc;
}

// 512 blocks x 256 threads: two threads per row. (R8-proven)
__global__ __launch_bounds__(256) void final_kernel(
    const float* __restrict__ Xa, const float* __restrict__ w2,
    const float* __restrict__ gamma, const float* __restrict__ beta,
    const float* __restrict__ lin2_w, const float* __restrict__ lin2_b,
    const float* __restrict__ T, const float* __restrict__ ws_partial,
    const float* __restrict__ ws_h, float* __restrict__ out)
{
    __shared__ float sg[64], sScale[8], sShift[8], sColw[8];
    __shared__ float sBsum;
    int tid = threadIdx.x;
    if (tid < 64) {
        sg[tid] = w2[tid] * (T[tid] * (1.f / 65536.f));
    } else if (tid < 72) {
        int j = tid - 64;
        float mu  = T[64 + j] * (1.f / 65536.f);
        float var = T[72 + j] * (1.f / 65536.f) - mu * mu;
        float sc = gamma[j] / sqrtf(var + BN_EPS);
        sScale[j] = sc;
        sShift[j] = beta[j] - mu * sc;
    } else if (tid < 80) {
        int j = tid - 72;
        sColw[j] = lin2_w[j] + lin2_w[8 + j] + lin2_w[16 + j] + lin2_w[24 + j];
    } else if (tid == 80) {
        sBsum = lin2_b[0] + lin2_b[1] + lin2_b[2] + lin2_b[3];
    }
    __syncthreads();

    int row  = (blockIdx.x * 256 + tid) >> 1;
    int half = tid & 1;
    int fo   = half * 32;

    const float4* xa4 = (const float4*)(Xa + (size_t)row * 64 + fo);
    float p2b = 0.f;
#pragma unroll
    for (int k = 0; k < 8; k++) {
        float4 vv = xa4[k];
        int b = fo + k * 4;
        p2b += vv.x * sg[b] + vv.y * sg[b + 1] + vv.z * sg[b + 2] + vv.w * sg[b + 3];
    }

    float4 hq = *(const float4*)(ws_h + (size_t)row * 8 + half * 4);
    float hv[4] = {hq.x, hq.y, hq.z, hq.w};
    float dmp = 0.f;
#pragma unroll
    for (int jj = 0; jj < 4; jj++) {
        int j = half * 4 + jj;
        float hn = tanhf(hv[jj] * sScale[j] + sShift[j]);
        dmp = fmaf(hn, sColw[j], dmp);
    }

    float val = p2b * (1.f / 64.f) + dmp * 0.25f;
    val += __shfl_xor(val, 1);
    if (!half)
        out[row] = val + ws_partial[row] + sBsum * 0.25f;
}

extern "C" void kernel_launch(void* const* d_in, const int* in_sizes, int n_in,
                              void* d_out, int out_size, void* d_ws, size_t ws_size,
                              hipStream_t stream) {
    const float* Xa        = (const float*)d_in[0];
    const float* Xc        = (const float*)d_in[1];
    const float* w1        = (const float*)d_in[2];
    const float* b1        = (const float*)d_in[3];
    const float* w2        = (const float*)d_in[4];
    const float* b2        = (const float*)d_in[5];
    const float* W1        = (const float*)d_in[6];
    const float* B1        = (const float*)d_in[7];
    const float* W2        = (const float*)d_in[8];
    const float* B2        = (const float*)d_in[9];
    const float* lin1_w    = (const float*)d_in[10];
    const float* lin1_b    = (const float*)d_in[11];
    const float* bn1_gamma = (const float*)d_in[12];
    const float* bn1_beta  = (const float*)d_in[13];
    const float* lin2_w    = (const float*)d_in[14];
    const float* lin2_b    = (const float*)d_in[15];

    float* ws  = (float*)d_ws;
    float* out = (float*)d_out;

    float* ws_partial = ws + OFF_PARTIAL;
    float* ws_h       = ws + OFF_H;
    float* ws_rec     = ws + OFF_REC;
    float* ws_blkT    = ws + OFF_BLKT;
    float* ws_T       = ws + OFF_T;

    precompute_kernel<<<64, 64, 0, stream>>>(W1, B1, W2, B2, lin1_w,
                                             w1, b1, b2, ws_rec);
    main_kernel<<<NBLK, 256, 0, stream>>>(Xa, Xc, ws_rec, lin1_b,
                                          ws_partial, ws_h, ws_blkT);
    reduce_kernel<<<20, 256, 0, stream>>>(ws_blkT, ws_T);
    final_kernel<<<512, 256, 0, stream>>>(Xa, w2, bn1_gamma, bn1_beta,
                                          lin2_w, lin2_b, ws_T,
                                          ws_partial, ws_h, out);
}